// Round 1
// 1686.169 us; speedup vs baseline: 1.0676x; 1.0676x over previous
//
#include <hip/hip_runtime.h>

typedef unsigned int u32;
typedef unsigned short u16;

#define BG 64
#define NNODE 320
#define NEDGE 1280
#define TT 256
#define FN 64
#define FG 16
#define HM 128
#define HU 128
#define HG 64
#define HA 4
#define ZM 512
#define ZU 512
#define ZG 256
#define ZA 16
#define DM 144
#define DU 208
#define DG 144
#define DA 192

// ---- conversion-area layout (floats, relative to ws+64) ----
#define CV 64
#define O_NODES 0
#define O_GA    20480
#define O_WM    21504
#define O_WHM   95232
#define O_BM    160768
#define O_WU    161280
#define O_WHU   267776
#define O_BU    333312
#define O_WG    333824
#define O_WHG   370688
#define O_BG2   387072
#define O_WA    387328
#define O_WHA   390400
#define O_BA    390464
#define CONV_TOTAL 390480
#define O_XZM   390528
#define O_XZU   (O_XZM + NEDGE * ZM)
#define O_XZG   (O_XZU + NNODE * ZU)
#define O_XZA   (O_XZG + BG * ZG)
#define O_AGGR  (O_XZA + BG * ZA)
#define O_AGGB  (O_AGGR + NNODE * HM)
#define O_UPD   (O_AGGB + BG * HU)
#define WS_FLOATS (CV + O_UPD + NNODE * HU)

__device__ __forceinline__ float bf2f(u16 v) {
  return __uint_as_float(((u32)v) << 16);
}
__device__ __forceinline__ float rcp_(float x) { return __builtin_amdgcn_rcpf(x); }
__device__ __forceinline__ float sigf(float x) { return rcp_(1.0f + __expf(-x)); }
__device__ __forceinline__ float tanh_(float x) {
  float e = __expf(-2.0f * fabsf(x));
  float t = (1.0f - e) * rcp_(1.0f + e);
  return copysignf(t, x);
}
__device__ __forceinline__ float cvt(const void* p, int i, int flag) {
  return flag ? bf2f(((const u16*)p)[i]) : ((const float*)p)[i];
}

// DPP cross-lane move (pure VALU, no DS pipe). CTRL: 0xB1 = quad_perm[1,0,3,2]
// (lane^1), 0x4E = quad_perm[2,3,0,1] (lane^2), 0x141 = row_half_mirror
// (lane^7 within each 8-lane half). {xor1, xor2, xor7} generates the full
// 8-lane group -> 3 rounds of s += dppmov(s) is an 8-lane all-reduce-sum.
template <int CTRL>
__device__ __forceinline__ float dppmov(float s) {
  return __int_as_float(
      __builtin_amdgcn_update_dpp(0, __float_as_int(s), CTRL, 0xF, 0xF, true));
}

// lgkmcnt-only barrier: LDS ordering without the vmcnt(0) drain that
// __syncthreads() emits. Global ops here are fire-and-forget stores (consumed
// by later kernels; visible at dispatch end) and prefetch loads (compiler
// inserts vmcnt wait at first use). See k_chain ordering proof in comments.
#define BAR() asm volatile("s_waitcnt lgkmcnt(0)\n\ts_barrier" ::: "memory")

// ---------------------------------------------------------------------------
// K-1: runtime dtype detector (unchanged; fp32 was detected).
// ---------------------------------------------------------------------------
__global__ void k_detect(const u32* __restrict__ raw, int* __restrict__ flagp) {
  const int t = threadIdx.x;  // 64 threads (1 wave)
  int zlo = 0, hits = 0;
  for (int k = t; k < 256; k += 64) {
    u32 w = raw[k];
    if ((w & 0xFFFFu) == 0u) zlo++;
    u32 m = (w >> 8) & 0x7Fu;
    if (m >= 40u && m <= 70u) hits++;
  }
#pragma unroll
  for (int off = 32; off; off >>= 1) {
    zlo += __shfl_down(zlo, off, 64);
    hits += __shfl_down(hits, off, 64);
  }
  if (t == 0) *flagp = (zlo < 128 && hits >= 128) ? 1 : 0;
}

// ---------------------------------------------------------------------------
// K0: convert weights/biases (+ t=255 slices) to fp32 in workspace.
// ---------------------------------------------------------------------------
__global__ __launch_bounds__(256) void k_convert(
    const void* nodes, const void* gattr,
    const void* Wm, const void* Whm, const void* bm1, const void* bm2,
    const void* Wu, const void* Whu, const void* bu1, const void* bu2,
    const void* Wg, const void* Whg, const void* bg1, const void* bg2,
    const void* Wa, const void* Wha, const void* ba1, const void* ba2,
    const int* __restrict__ flagp, float* __restrict__ dst) {
  const int flag = *flagp;
  const int i = blockIdx.x * 256 + threadIdx.x;
  if (i >= CONV_TOTAL) return;
  float v;
  if (i < O_GA) {
    int n = i >> 6, f = i & 63;
    v = cvt(nodes, (n * TT + (TT - 1)) * FN + f, flag);
  } else if (i < O_WM) {
    int l = i - O_GA; int b = l >> 4, g = l & 15;
    v = cvt(gattr, (b * TT + (TT - 1)) * FG + g, flag);
  } else if (i < O_BM) {
    v = (i < O_WHM) ? cvt(Wm, i - O_WM, flag) : cvt(Whm, i - O_WHM, flag);
  } else if (i < O_WU) {
    int l = i - O_BM; v = cvt(bm1, l, flag) + cvt(bm2, l, flag);
  } else if (i < O_BU) {
    v = (i < O_WHU) ? cvt(Wu, i - O_WU, flag) : cvt(Whu, i - O_WHU, flag);
  } else if (i < O_WG) {
    int l = i - O_BU; v = cvt(bu1, l, flag) + cvt(bu2, l, flag);
  } else if (i < O_BG2) {
    v = (i < O_WHG) ? cvt(Wg, i - O_WG, flag) : cvt(Whg, i - O_WHG, flag);
  } else if (i < O_WA) {
    int l = i - O_BG2; v = cvt(bg1, l, flag) + cvt(bg2, l, flag);
  } else if (i < O_WHA) {
    v = cvt(Wa, i - O_WA, flag);
  } else if (i < O_BA) {
    v = cvt(Wha, i - O_WHA, flag);
  } else {
    int l = i - O_BA; v = cvt(ba1, l, flag) + cvt(ba2, l, flag);
  }
  dst[i] = v;
}

// ---------------------------------------------------------------------------
// K1: parallel precompute of input projections at t = T-1 (unchanged).
// ---------------------------------------------------------------------------
__global__ __launch_bounds__(256) void k_pre(
    const float* __restrict__ cva,
    const int* __restrict__ eidx, const int* __restrict__ num_nodes,
    const int* __restrict__ num_edges,
    float* __restrict__ XZm, float* __restrict__ XZu, float* __restrict__ XZg) {
  const int blk = blockIdx.x, tid = threadIdx.x;
  __shared__ float xv[FN];
  __shared__ float gav[FG];
  __shared__ int sgr;
  const float* nodes255 = cva + O_NODES;
  const float* ga255 = cva + O_GA;

  if (blk < NEDGE) {
    const int e = blk;
    if (tid == 0) {
      int g = 0, acc = 0;
      while (g < BG) { int c = num_edges[g]; if (e < acc + c) break; acc += c; ++g; }
      if (g >= BG) g = BG - 1;
      sgr = g;
    }
    const int srcn = eidx[e];  // faithful: src == tgt == edge_indices[0]
    if (tid < FN) xv[tid] = nodes255[srcn * FN + tid];
    __syncthreads();
    if (tid < FG) gav[tid] = ga255[sgr * FG + tid];
    __syncthreads();
    for (int j = tid; j < ZM; j += 256) {
      const float* wr = cva + O_WM + j * DM;
      float acc = cva[O_BM + j];
#pragma unroll
      for (int d = 0; d < FN; ++d) acc += (wr[d] + wr[FN + d]) * xv[d];
#pragma unroll
      for (int d = 0; d < FG; ++d) acc += wr[2 * FN + d] * gav[d];
      XZm[(size_t)e * ZM + j] = acc;
    }
  } else if (blk < NEDGE + NNODE) {
    const int n = blk - NEDGE;
    if (tid == 0) {
      int g = 0, acc = 0;
      while (g < BG) { int c = num_nodes[g]; if (n < acc + c) break; acc += c; ++g; }
      if (g >= BG) g = BG - 1;
      sgr = g;
    }
    if (tid < FN) xv[tid] = nodes255[n * FN + tid];
    __syncthreads();
    if (tid < FG) gav[tid] = ga255[sgr * FG + tid];
    __syncthreads();
    for (int j = tid; j < ZU; j += 256) {
      const float* wr = cva + O_WU + j * DU;
      float acc = cva[O_BU + j];
#pragma unroll
      for (int d = 0; d < FN; ++d) acc += wr[d] * xv[d];
#pragma unroll
      for (int d = 0; d < FG; ++d) acc += wr[FN + HM + d] * gav[d];
      XZu[(size_t)n * ZU + j] = acc;
    }
  } else {
    const int b = blk - NEDGE - NNODE;
    if (tid < FG) gav[tid] = ga255[b * FG + tid];
    __syncthreads();
    if (tid < ZG) {
      const float* wr = cva + O_WG + tid * DG;
      float acc = cva[O_BG2 + tid];
#pragma unroll
      for (int d = 0; d < FG; ++d) acc += wr[HU + d] * gav[d];
      XZg[(size_t)b * ZG + tid] = acc;
    }
  }
}

// ---------------------------------------------------------------------------
// K2/K4: LSTM chain, lane-parallel-k formulation. 1024 threads, 1 block,
// 16 waves. Group = 8 lanes (kc = lane&7 -> k-chunk of 16). Group g of wave
// w owns element e = w*8+g; pass p in [0,4) computes row p*128+e = gate p.
// 8-way k-split -> only 64 Whh floats per lane: fits the 128-reg arch-VGPR
// budget at 4 waves/SIMD, so the compiler cannot demote the weight tile to
// AGPRs (the 512-thread/128-float version allocated only 84 arch VGPRs ->
// per-step accvgpr traffic, the dominant VALU overhead).
// Reduce = 3 DPP rounds (xor1, xor2, half-mirror) -> pure VALU, no DS pipe.
// h double-buffered in LDS: 8 chunks x 20 floats (16 + 4 pad); the 8
// distinct b128 read addresses cover all 32 banks exactly once.
// Ordering proof for overlay (k_msg: hout overlays XZ region):
//   store of step e-1's h at step e touches XZ floats [(e-1)*128,(e)*128)
//   i.e. XZ row (e-1)/4 <= e-1; every wave consumed that row's loads
//   (vmcnt-waited at its z compute) before passing barrier e-1; prefetch at
//   step e reads row e+1 > (e-1)/4. No in-flight load can see the store.
// ---------------------------------------------------------------------------
template <int STEPS>
__global__ __launch_bounds__(1024, 4) void k_chain(
    const float* __restrict__ Whh, const float* __restrict__ XZ,
    float* __restrict__ hout) {
  const int lane = threadIdx.x & 63;
  const int wv = threadIdx.x >> 6;  // wave 0..15
  const int kc = lane & 7;          // k-chunk 0..7 (16 floats each)
  const int g = lane >> 3;          // group-in-wave 0..7
  const int elem = wv * 8 + g;      // element 0..127
  __shared__ float hbuf[2][8 * 20];  // 8 chunks x (16 + 4 pad)

  float wreg[64];  // Whh rows {p*128+elem}, cols kc*16..+15
#pragma unroll
  for (int p = 0; p < 4; ++p) {
    const float4* wr =
        (const float4*)(Whh + (size_t)(p * 128 + elem) * 128 + kc * 16);
#pragma unroll
    for (int q = 0; q < 4; ++q) {
      float4 t = wr[q];
      wreg[p * 16 + q * 4 + 0] = t.x;
      wreg[p * 16 + q * 4 + 1] = t.y;
      wreg[p * 16 + q * 4 + 2] = t.z;
      wreg[p * 16 + q * 4 + 3] = t.w;
    }
  }
  if (threadIdx.x < 160) hbuf[0][threadIdx.x] = 0.0f;
  float c = 0.0f;
  float hrelu_prev = 0.0f;
  float xz[4];
#pragma unroll
  for (int p = 0; p < 4; ++p) xz[p] = XZ[p * 128 + elem];
  BAR();
  int cur = 0;
  for (int e = 0; e < STEPS; ++e) {
    // h chunk (16 floats) from LDS, conflict-free b128 broadcast
    float hv[16];
    const float4* hb = (const float4*)&hbuf[cur][kc * 20];
#pragma unroll
    for (int q = 0; q < 4; ++q) {
      float4 t = hb[q];
      hv[q * 4 + 0] = t.x; hv[q * 4 + 1] = t.y;
      hv[q * 4 + 2] = t.z; hv[q * 4 + 3] = t.w;
    }
    float z[4];
#pragma unroll
    for (int p = 0; p < 4; ++p) {
      float a0 = 0.0f, a1 = 0.0f;
#pragma unroll
      for (int k = 0; k < 8; ++k) {
        a0 += wreg[p * 16 + k] * hv[k];
        a1 += wreg[p * 16 + 8 + k] * hv[8 + k];
      }
      float s = a0 + a1;
      s += dppmov<0xB1>(s);   // lane^1
      s += dppmov<0x4E>(s);   // lane^2
      s += dppmov<0x141>(s);  // lane^7 (half mirror) -> 8-lane all-sum
      z[p] = xz[p] + s;
    }
    // prefetch next step's XZ (no barrier dependency; vmcnt at next use)
    if (e + 1 < STEPS) {
      const float* xp = XZ + (size_t)(e + 1) * 512;
#pragma unroll
      for (int p = 0; p < 4; ++p) xz[p] = xp[p * 128 + elem];
    }
    // gates: z[0]=i, z[1]=f, z[2]=g, z[3]=o (replicated across group)
    float si = sigf(z[0]), sf = sigf(z[1]), so = sigf(z[3]);
    float tg = tanh_(z[2]);
    c = sf * c + si * tg;
    float h = so * tanh_(c);
    if (kc == 0) {
      hbuf[cur ^ 1][(elem >> 4) * 20 + (elem & 15)] = h;
      if (e > 0) hout[(size_t)(e - 1) * 128 + elem] = hrelu_prev;
      hrelu_prev = fmaxf(h, 0.0f);
    }
    BAR();
    cur ^= 1;
  }
  if (kc == 0) hout[(size_t)(STEPS - 1) * 128 + elem] = hrelu_prev;
}

// ---------------------------------------------------------------------------
// K2b: generic segment_min over edges: aggr[n] = min_{e: eidx[e]==n} msg[e]
// ---------------------------------------------------------------------------
__global__ __launch_bounds__(128) void k_aggmin(
    const float* __restrict__ msg, const int* __restrict__ eidx,
    float* __restrict__ aggr) {
  const int n = blockIdx.x, j = threadIdx.x;
  float m = __uint_as_float(0x7f800000u);  // +inf (segment_min identity)
  for (int e = 0; e < NEDGE; ++e) {
    if (eidx[e] == n) m = fminf(m, msg[(size_t)e * HM + j]);
  }
  aggr[(size_t)n * HM + j] = m;
}

// ---------------------------------------------------------------------------
// K3: XZu[n] += Wih_u[:,64:192] @ aggr[n]   (parallel, 320 blocks)
// ---------------------------------------------------------------------------
__global__ __launch_bounds__(256) void k_aggproj(
    const float* __restrict__ cva, const float* __restrict__ aggr,
    float* __restrict__ XZu) {
  const int n = blockIdx.x, tid = threadIdx.x;
  __shared__ float av[HM];
  if (tid < HM) av[tid] = aggr[(size_t)n * HM + tid];
  __syncthreads();
  for (int j = tid; j < ZU; j += 256) {
    const float* wr = cva + O_WU + j * DU + FN;
    float acc = 0.0f;
#pragma unroll
    for (int k = 0; k < HM; ++k) acc += wr[k] * av[k];
    XZu[(size_t)n * ZU + j] += acc;
  }
}

// ---------------------------------------------------------------------------
// K4b: generic segment_min over nodes: aggB[b] = min_{n: bidx[n]==b} upd[n]
// ---------------------------------------------------------------------------
__global__ __launch_bounds__(128) void k_aggbmin(
    const float* __restrict__ upd, const int* __restrict__ bidx,
    float* __restrict__ aggB) {
  const int b = blockIdx.x, j = threadIdx.x;
  float m = __uint_as_float(0x7f800000u);
  for (int n = 0; n < NNODE; ++n) {
    if (bidx[n] == b) m = fminf(m, upd[(size_t)n * HU + j]);
  }
  aggB[(size_t)b * HU + j] = m;
}

// ---------------------------------------------------------------------------
// K5: blocks [0,64): XZg[b] += Wih_g[:,0:128] @ aggB[b]
//     blocks [64,128): XZa[b] = Wih_a[:,0:128] @ chosen[b] + biases
// ---------------------------------------------------------------------------
__global__ __launch_bounds__(256) void k_gproj(
    const float* __restrict__ cva,
    const float* __restrict__ aggB, const float* __restrict__ upd,
    const int* __restrict__ bidx, const int* __restrict__ who,
    float* __restrict__ XZg, float* __restrict__ XZa) {
  const int blk = blockIdx.x, tid = threadIdx.x;
  __shared__ float buf[HU];
  __shared__ int satbw;
  if (blk < BG) {
    const int b = blk;
    if (tid < HU) buf[tid] = aggB[(size_t)b * HU + tid];
    __syncthreads();
    if (tid < ZG) {
      const float* wr = cva + O_WG + tid * DG;
      float acc = 0.0f;
#pragma unroll
      for (int k = 0; k < HU; ++k) acc += wr[k] * buf[k];
      XZg[(size_t)b * ZG + tid] += acc;
    }
  } else {
    const int b = blk - BG;
    const int whoB = who[b];
    if (tid == 0) {
      int off = 0;
      for (int i = 0; i < NNODE; ++i) off += (bidx[i] < b) ? 1 : 0;
      const int adj = (whoB == 3) ? 2 : whoB;
      satbw = (b == 0) ? who[0] : (adj + off);
    }
    __syncthreads();
    if (tid < HU) {
      float v;
      if (whoB == 3) v = aggB[(size_t)b * HU + tid];
      else v = upd[(size_t)satbw * HU + tid];
      buf[tid] = v;
    }
    __syncthreads();
    if (tid < ZA) {
      const float* wr = cva + O_WA + tid * DA;
      float acc = cva[O_BA + tid];
#pragma unroll
      for (int k = 0; k < HU; ++k) acc += wr[k] * buf[k];
      XZa[(size_t)b * ZA + tid] = acc;
    }
  }
}

// ---------------------------------------------------------------------------
// K6: group LSTM chain (64 steps, H=64) + action chain + softmax + fp32 out.
// ---------------------------------------------------------------------------
__global__ __launch_bounds__(256, 2) void k_final(
    const float* __restrict__ cva, const float* __restrict__ XZg,
    const float* __restrict__ XZa, float* __restrict__ out) {
  const int j = threadIdx.x;
  __shared__ __align__(16) float hg[HG];
  __shared__ float zsg[ZG];
  __shared__ float grp[BG * HG];
  __shared__ float za[ZA];
  __shared__ float haL[HA];
  __shared__ float res[BG * HA];

  float wg[HG];
  {
    const float* wr = cva + O_WHG + j * HG;
#pragma unroll
    for (int k = 0; k < HG; ++k) wg[k] = wr[k];
  }
  if (j < HG) hg[j] = 0.0f;
  float cg = 0.0f;
  __syncthreads();
  for (int b = 0; b < BG; ++b) {
    float acc = XZg[(size_t)b * ZG + j];
#pragma unroll
    for (int k = 0; k < HG; ++k) acc += wg[k] * hg[k];
    zsg[j] = acc;
    __syncthreads();
    if (j < HG) {
      float zi = zsg[j], zf = zsg[HG + j], zg = zsg[2 * HG + j], zo = zsg[3 * HG + j];
      cg = sigf(zf) * cg + sigf(zi) * tanh_(zg);
      float h = sigf(zo) * tanh_(cg);
      hg[j] = h;
      grp[b * HG + j] = fmaxf(h, 0.0f);
    }
    __syncthreads();
  }

  float wa2[HG];
  float wha[HA];
  if (j < ZA) {
    const float* wr2 = cva + O_WA + j * DA + HU;
#pragma unroll
    for (int k = 0; k < HG; ++k) wa2[k] = wr2[k];
#pragma unroll
    for (int k = 0; k < HA; ++k) wha[k] = cva[O_WHA + j * HA + k];
  }
  if (j < HA) haL[j] = 0.0f;
  float ca = 0.0f;
  __syncthreads();
  for (int b = 0; b < BG; ++b) {
    if (j < ZA) {
      float acc = XZa[(size_t)b * ZA + j];
#pragma unroll
      for (int k = 0; k < HG; ++k) acc += wa2[k] * grp[b * HG + k];
#pragma unroll
      for (int k = 0; k < HA; ++k) acc += wha[k] * haL[k];
      za[j] = acc;
    }
    __syncthreads();
    if (j < HA) {
      float zi = za[j], zf = za[HA + j], zg = za[2 * HA + j], zo = za[3 * HA + j];
      ca = sigf(zf) * ca + sigf(zi) * tanh_(zg);
      float h = sigf(zo) * tanh_(ca);
      haL[j] = h;
      res[b * HA + j] = h;
    }
    __syncthreads();
  }
  if (j < BG) {
    float x0 = res[j * 4 + 0], x1 = res[j * 4 + 1];
    float x2 = res[j * 4 + 2], x3 = res[j * 4 + 3];
    float m = fmaxf(fmaxf(x0, x1), fmaxf(x2, x3));
    float e0 = __expf(x0 - m), e1 = __expf(x1 - m);
    float e2 = __expf(x2 - m), e3 = __expf(x3 - m);
    float s = e0 + e1 + e2 + e3;
    out[j * 4 + 0] = e0 / s;
    out[j * 4 + 1] = e1 / s;
    out[j * 4 + 2] = e2 / s;
    out[j * 4 + 3] = e3 / s;
  }
}

__global__ void k_zero(float* out) { out[threadIdx.x] = 0.0f; }

extern "C" void kernel_launch(void* const* d_in, const int* in_sizes, int n_in,
                              void* d_out, int out_size, void* d_ws, size_t ws_size,
                              hipStream_t stream) {
  const void* nodes = d_in[0];
  const void* gattr = d_in[1];
  const int* eidx  = (const int*)d_in[2];
  const int* nn    = (const int*)d_in[3];
  const int* ne    = (const int*)d_in[4];
  const int* bidx  = (const int*)d_in[5];
  const int* who   = (const int*)d_in[6];

  if (ws_size < (size_t)WS_FLOATS * 4) {
    k_zero<<<1, 256, 0, stream>>>((float*)d_out);
    return;
  }

  float* ws = (float*)d_ws;
  int* flagp = (int*)d_ws;
  float* cva = ws + CV;
  float* XZm = cva + O_XZM;
  float* XZu = cva + O_XZU;
  float* XZg = cva + O_XZG;
  float* XZa = cva + O_XZA;
  float* aggr = cva + O_AGGR;
  float* aggB = cva + O_AGGB;
  float* upd = cva + O_UPD;
  float* msg = XZm;  // overlay (delayed-store ordering; see k_chain comment)

  k_detect<<<1, 64, 0, stream>>>((const u32*)nodes, flagp);
  k_convert<<<(CONV_TOTAL + 255) / 256, 256, 0, stream>>>(
      nodes, gattr,
      d_in[7], d_in[8], d_in[9], d_in[10],
      d_in[11], d_in[12], d_in[13], d_in[14],
      d_in[15], d_in[16], d_in[17], d_in[18],
      d_in[19], d_in[20], d_in[21], d_in[22],
      flagp, cva);
  k_pre<<<NEDGE + NNODE + BG, 256, 0, stream>>>(cva, eidx, nn, ne, XZm, XZu, XZg);
  k_chain<NEDGE><<<1, 1024, 0, stream>>>(cva + O_WHM, XZm, msg);
  k_aggmin<<<NNODE, 128, 0, stream>>>(msg, eidx, aggr);
  k_aggproj<<<NNODE, 256, 0, stream>>>(cva, aggr, XZu);
  k_chain<NNODE><<<1, 1024, 0, stream>>>(cva + O_WHU, XZu, upd);
  k_aggbmin<<<BG, 128, 0, stream>>>(upd, bidx, aggB);
  k_gproj<<<2 * BG, 256, 0, stream>>>(cva, aggB, upd, bidx, who, XZg, XZa);
  k_final<<<1, 256, 0, stream>>>(cva, XZg, XZa, (float*)d_out);
}

// Round 2
// 1385.081 us; speedup vs baseline: 1.2997x; 1.2174x over previous
//
#include <hip/hip_runtime.h>

typedef unsigned int u32;
typedef unsigned short u16;

#define BG 64
#define NNODE 320
#define NEDGE 1280
#define TT 256
#define FN 64
#define FG 16
#define HM 128
#define HU 128
#define HG 64
#define HA 4
#define ZM 512
#define ZU 512
#define ZG 256
#define ZA 16
#define DM 144
#define DU 208
#define DG 144
#define DA 192

// ---- conversion-area layout (floats, relative to ws+64) ----
#define CV 64
#define O_NODES 0
#define O_GA    20480
#define O_WM    21504
#define O_WHM   95232
#define O_BM    160768
#define O_WU    161280
#define O_WHU   267776
#define O_BU    333312
#define O_WG    333824
#define O_WHG   370688
#define O_BG2   387072
#define O_WA    387328
#define O_WHA   390400
#define O_BA    390464
#define CONV_TOTAL 390480
#define O_XZM   390528
#define O_XZU   (O_XZM + NEDGE * ZM)
#define O_XZG   (O_XZU + NNODE * ZU)
#define O_XZA   (O_XZG + BG * ZG)
#define O_AGGR  (O_XZA + BG * ZA)
#define O_AGGB  (O_AGGR + NNODE * HM)
#define O_UPD   (O_AGGB + BG * HU)
#define WS_FLOATS (CV + O_UPD + NNODE * HU)

__device__ __forceinline__ float bf2f(u16 v) {
  return __uint_as_float(((u32)v) << 16);
}
__device__ __forceinline__ float rcp_(float x) { return __builtin_amdgcn_rcpf(x); }
__device__ __forceinline__ float sigf(float x) { return rcp_(1.0f + __expf(-x)); }
__device__ __forceinline__ float tanh_(float x) {
  float e = __expf(-2.0f * fabsf(x));
  float t = (1.0f - e) * rcp_(1.0f + e);
  return copysignf(t, x);
}
__device__ __forceinline__ float cvt(const void* p, int i, int flag) {
  return flag ? bf2f(((const u16*)p)[i]) : ((const float*)p)[i];
}

// DPP cross-lane move (pure VALU, no DS pipe). quad_perm encodings:
// 0xB1 = [1,0,3,2] (lane^1), 0x4E = [2,3,0,1] (lane^2), 0x1B = [3,2,1,0] (lane^3).
template <int CTRL>
__device__ __forceinline__ float dppmov(float s) {
  return __int_as_float(
      __builtin_amdgcn_update_dpp(0, __float_as_int(s), CTRL, 0xF, 0xF, true));
}

// Arch-VGPR-pinned fused MAC: "v" constraint class excludes AGPRs, so the
// weight stream cannot be demoted to accvgprs (round-0/1 showed the compiler
// splitting the weight array off the arch file: VGPR_Count 84/48 with a
// 128/64-float array -> per-use accvgpr traffic, ~2x the MAC issue cost).
#define FMAC(acc, x, y) \
  asm("v_fmac_f32 %0, %1, %2" : "+v"(acc) : "v"(x), "v"(y))

// lgkmcnt-only barrier: LDS ordering without the vmcnt(0) drain that
// __syncthreads() emits. Global ops here are fire-and-forget stores (consumed
// by later kernels; visible at dispatch end) and prefetch loads (compiler
// inserts vmcnt wait at first use). See k_chain ordering proof in comments.
#define BAR() asm volatile("s_waitcnt lgkmcnt(0)\n\ts_barrier" ::: "memory")

// ---------------------------------------------------------------------------
// K-1: runtime dtype detector (unchanged; fp32 was detected).
// ---------------------------------------------------------------------------
__global__ void k_detect(const u32* __restrict__ raw, int* __restrict__ flagp) {
  const int t = threadIdx.x;  // 64 threads (1 wave)
  int zlo = 0, hits = 0;
  for (int k = t; k < 256; k += 64) {
    u32 w = raw[k];
    if ((w & 0xFFFFu) == 0u) zlo++;
    u32 m = (w >> 8) & 0x7Fu;
    if (m >= 40u && m <= 70u) hits++;
  }
#pragma unroll
  for (int off = 32; off; off >>= 1) {
    zlo += __shfl_down(zlo, off, 64);
    hits += __shfl_down(hits, off, 64);
  }
  if (t == 0) *flagp = (zlo < 128 && hits >= 128) ? 1 : 0;
}

// ---------------------------------------------------------------------------
// K0: convert weights/biases (+ t=255 slices) to fp32 in workspace.
// ---------------------------------------------------------------------------
__global__ __launch_bounds__(256) void k_convert(
    const void* nodes, const void* gattr,
    const void* Wm, const void* Whm, const void* bm1, const void* bm2,
    const void* Wu, const void* Whu, const void* bu1, const void* bu2,
    const void* Wg, const void* Whg, const void* bg1, const void* bg2,
    const void* Wa, const void* Wha, const void* ba1, const void* ba2,
    const int* __restrict__ flagp, float* __restrict__ dst) {
  const int flag = *flagp;
  const int i = blockIdx.x * 256 + threadIdx.x;
  if (i >= CONV_TOTAL) return;
  float v;
  if (i < O_GA) {
    int n = i >> 6, f = i & 63;
    v = cvt(nodes, (n * TT + (TT - 1)) * FN + f, flag);
  } else if (i < O_WM) {
    int l = i - O_GA; int b = l >> 4, g = l & 15;
    v = cvt(gattr, (b * TT + (TT - 1)) * FG + g, flag);
  } else if (i < O_BM) {
    v = (i < O_WHM) ? cvt(Wm, i - O_WM, flag) : cvt(Whm, i - O_WHM, flag);
  } else if (i < O_WU) {
    int l = i - O_BM; v = cvt(bm1, l, flag) + cvt(bm2, l, flag);
  } else if (i < O_BU) {
    v = (i < O_WHU) ? cvt(Wu, i - O_WU, flag) : cvt(Whu, i - O_WHU, flag);
  } else if (i < O_WG) {
    int l = i - O_BU; v = cvt(bu1, l, flag) + cvt(bu2, l, flag);
  } else if (i < O_BG2) {
    v = (i < O_WHG) ? cvt(Wg, i - O_WG, flag) : cvt(Whg, i - O_WHG, flag);
  } else if (i < O_WA) {
    int l = i - O_BG2; v = cvt(bg1, l, flag) + cvt(bg2, l, flag);
  } else if (i < O_WHA) {
    v = cvt(Wa, i - O_WA, flag);
  } else if (i < O_BA) {
    v = cvt(Wha, i - O_WHA, flag);
  } else {
    int l = i - O_BA; v = cvt(ba1, l, flag) + cvt(ba2, l, flag);
  }
  dst[i] = v;
}

// ---------------------------------------------------------------------------
// K1: parallel precompute of input projections at t = T-1 (unchanged).
// ---------------------------------------------------------------------------
__global__ __launch_bounds__(256) void k_pre(
    const float* __restrict__ cva,
    const int* __restrict__ eidx, const int* __restrict__ num_nodes,
    const int* __restrict__ num_edges,
    float* __restrict__ XZm, float* __restrict__ XZu, float* __restrict__ XZg) {
  const int blk = blockIdx.x, tid = threadIdx.x;
  __shared__ float xv[FN];
  __shared__ float gav[FG];
  __shared__ int sgr;
  const float* nodes255 = cva + O_NODES;
  const float* ga255 = cva + O_GA;

  if (blk < NEDGE) {
    const int e = blk;
    if (tid == 0) {
      int g = 0, acc = 0;
      while (g < BG) { int c = num_edges[g]; if (e < acc + c) break; acc += c; ++g; }
      if (g >= BG) g = BG - 1;
      sgr = g;
    }
    const int srcn = eidx[e];  // faithful: src == tgt == edge_indices[0]
    if (tid < FN) xv[tid] = nodes255[srcn * FN + tid];
    __syncthreads();
    if (tid < FG) gav[tid] = ga255[sgr * FG + tid];
    __syncthreads();
    for (int j = tid; j < ZM; j += 256) {
      const float* wr = cva + O_WM + j * DM;
      float acc = cva[O_BM + j];
#pragma unroll
      for (int d = 0; d < FN; ++d) acc += (wr[d] + wr[FN + d]) * xv[d];
#pragma unroll
      for (int d = 0; d < FG; ++d) acc += wr[2 * FN + d] * gav[d];
      XZm[(size_t)e * ZM + j] = acc;
    }
  } else if (blk < NEDGE + NNODE) {
    const int n = blk - NEDGE;
    if (tid == 0) {
      int g = 0, acc = 0;
      while (g < BG) { int c = num_nodes[g]; if (n < acc + c) break; acc += c; ++g; }
      if (g >= BG) g = BG - 1;
      sgr = g;
    }
    if (tid < FN) xv[tid] = nodes255[n * FN + tid];
    __syncthreads();
    if (tid < FG) gav[tid] = ga255[sgr * FG + tid];
    __syncthreads();
    for (int j = tid; j < ZU; j += 256) {
      const float* wr = cva + O_WU + j * DU;
      float acc = cva[O_BU + j];
#pragma unroll
      for (int d = 0; d < FN; ++d) acc += wr[d] * xv[d];
#pragma unroll
      for (int d = 0; d < FG; ++d) acc += wr[FN + HM + d] * gav[d];
      XZu[(size_t)n * ZU + j] = acc;
    }
  } else {
    const int b = blk - NEDGE - NNODE;
    if (tid < FG) gav[tid] = ga255[b * FG + tid];
    __syncthreads();
    if (tid < ZG) {
      const float* wr = cva + O_WG + tid * DG;
      float acc = cva[O_BG2 + tid];
#pragma unroll
      for (int d = 0; d < FG; ++d) acc += wr[HU + d] * gav[d];
      XZg[(size_t)b * ZG + tid] = acc;
    }
  }
}

// ---------------------------------------------------------------------------
// K2/K4: LSTM chain. 1024 threads (16 waves), issue-count-minimized form.
//
// Layout: 8-lane group = {quad q, quad q^32}: kc = (lane&3)|((lane&32)>>3)
// selects a 16-float k-chunk of h; elem = wv*8 + ((lane>>2)&7). Each lane
// computes 4 gate-partials (64 asm-pinned v_fmac), then a 3-round
// REDUCE-SCATTER (^1, ^2 via quad_perm DPP; ^32 via shfl) leaves
// z[gate p = lane&3] one-per-lane. Each lane then runs ONE unified
// nonlinearity (sigmoid for p in {0,1,3}, tanh for p==2, selected by
// per-lane constants) -> 1 exp + 1 rcp per lane instead of 4+4.
// c/h are assembled in the p==0 lanes via 3 quad_perm gathers; per-lane xz
// load is 1 float (own gate) instead of 4.
//
// h double-buffered in LDS: 8 chunks x 20 floats (16 + 4 pad); the 8
// distinct b128 read addresses cover all 32 banks exactly once.
// Ordering proof for overlay (k_msg: hout overlays XZ region):
//   store of step e-1's h at step e touches XZ floats [(e-1)*128,(e)*128)
//   i.e. XZ row (e-1)/4 <= e-1; every wave consumed that row's loads
//   (vmcnt-waited at its z compute) before passing barrier e-1; prefetch at
//   step e reads row e+1 > (e-1)/4. No in-flight load can see the store.
//   Unconditional prefetch of row STEPS reads one row past XZ: still inside
//   the workspace (XZu follows XZm, XZg follows XZu); value unused.
// ---------------------------------------------------------------------------
template <int STEPS>
__global__ __launch_bounds__(1024, 4) void k_chain(
    const float* __restrict__ Whh, const float* __restrict__ XZ,
    float* __restrict__ hout) {
  const int lane = threadIdx.x & 63;
  const int wv = threadIdx.x >> 6;               // wave 0..15
  const int p = lane & 3;                        // gate this lane finalizes
  const int kc = (lane & 3) | ((lane & 32) >> 3);  // k-chunk 0..7
  const int elem = wv * 8 + ((lane >> 2) & 7);   // element 0..127
  const bool islead = (p == 0) && (lane < 32);   // 1 lane per element
  __shared__ float hbuf[2][160];                 // 8 chunks x (16 + 4 pad)

  float wreg[64];  // Whh rows {pp*128+elem}, cols kc*16..+15, pp=0..3
#pragma unroll
  for (int pp = 0; pp < 4; ++pp) {
    const float4* wr =
        (const float4*)(Whh + (size_t)(pp * 128 + elem) * 128 + kc * 16);
#pragma unroll
    for (int q = 0; q < 4; ++q) {
      float4 t = wr[q];
      wreg[pp * 16 + q * 4 + 0] = t.x;
      wreg[pp * 16 + q * 4 + 1] = t.y;
      wreg[pp * 16 + q * 4 + 2] = t.z;
      wreg[pp * 16 + q * 4 + 3] = t.w;
    }
  }
  // per-lane nonlinearity constants: sigmoid(z)=rcp(1+exp2(-z*log2e));
  // tanh(z)=2*rcp(1+exp2(-2z*log2e))-1. Unified: fma(smul, rcp(1+exp2(z*kmul)), badd)
  const float LOG2E = 1.4426950408889634f;
  const float kmul = (p == 2) ? (-2.0f * LOG2E) : (-LOG2E);
  const float smul = (p == 2) ? 2.0f : 1.0f;
  const float badd = (p == 2) ? -1.0f : 0.0f;
  const float KT2 = -2.0f * LOG2E;  // for tanh(c)

  if (threadIdx.x < 160) hbuf[0][threadIdx.x] = 0.0f;
  float c = 0.0f;
  float hrelu_prev = 0.0f;
  float xz = XZ[p * 128 + elem];
  BAR();
  int cur = 0;
  for (int e = 0; e < STEPS; ++e) {
    // h chunk (16 floats) from LDS, conflict-free b128 broadcast
    float hv[16];
    const float4* hb = (const float4*)&hbuf[cur][kc * 20];
#pragma unroll
    for (int q = 0; q < 4; ++q) {
      float4 t = hb[q];
      hv[q * 4 + 0] = t.x; hv[q * 4 + 1] = t.y;
      hv[q * 4 + 2] = t.z; hv[q * 4 + 3] = t.w;
    }
    // 8 independent fmac chains (4 gates x 2 halves), arch-VGPR pinned
    float a0 = 0.0f, a1 = 0.0f, a2 = 0.0f, a3 = 0.0f;
    float a4 = 0.0f, a5 = 0.0f, a6 = 0.0f, a7 = 0.0f;
#pragma unroll
    for (int k = 0; k < 8; ++k) {
      FMAC(a0, wreg[0 * 16 + k], hv[k]); FMAC(a1, wreg[0 * 16 + 8 + k], hv[8 + k]);
      FMAC(a2, wreg[1 * 16 + k], hv[k]); FMAC(a3, wreg[1 * 16 + 8 + k], hv[8 + k]);
      FMAC(a4, wreg[2 * 16 + k], hv[k]); FMAC(a5, wreg[2 * 16 + 8 + k], hv[8 + k]);
      FMAC(a6, wreg[3 * 16 + k], hv[k]); FMAC(a7, wreg[3 * 16 + 8 + k], hv[8 + k]);
    }
    // reduce-scatter: after this, z holds gate (lane&3) of elem, summed
    // over the 8-lane group. Exchange pattern: send my DISCARDED value
    // (= partner's kept gate), receive partner's discarded (= my kept).
    float pa0 = a0 + a1, pa1 = a2 + a3, pa2 = a4 + a5, pa3 = a6 + a7;
    const bool o0 = (lane & 1) != 0, o1 = (lane & 2) != 0;
    float u0 = o0 ? pa1 : pa0, d0 = o0 ? pa0 : pa1;
    float u1 = o0 ? pa3 : pa2, d1 = o0 ? pa2 : pa3;
    u0 += dppmov<0xB1>(d0);
    u1 += dppmov<0xB1>(d1);
    float uu = o1 ? u1 : u0, dd = o1 ? u0 : u1;
    uu += dppmov<0x4E>(dd);
    float z = uu + __shfl_xor(uu, 32, 64) + xz;
    // prefetch next step's xz (own gate only; vmcnt at next use)
    xz = XZ[(size_t)(e + 1) * 512 + p * 128 + elem];
    // unified per-lane gate nonlinearity
    float ex = __builtin_amdgcn_exp2f(z * kmul);
    float gq = __builtin_fmaf(smul, rcp_(1.0f + ex), badd);
    // assemble c,h in p==0 lanes (others compute garbage, never read)
    float gf = dppmov<0xB1>(gq);  // sigmoid(zf) from lane^1
    float gt = dppmov<0x4E>(gq);  // tanh(zg)    from lane^2
    float go = dppmov<0x1B>(gq);  // sigmoid(zo) from lane^3
    c = __builtin_fmaf(gf, c, gq * gt);
    float ec = __builtin_amdgcn_exp2f(c * KT2);
    float th = __builtin_fmaf(2.0f, rcp_(1.0f + ec), -1.0f);
    float h = go * th;
    if (islead) {
      hbuf[cur ^ 1][(elem >> 4) * 20 + (elem & 15)] = h;
      if (e > 0) hout[(size_t)(e - 1) * 128 + elem] = hrelu_prev;
      hrelu_prev = fmaxf(h, 0.0f);
    }
    BAR();
    cur ^= 1;
  }
  if (islead) hout[(size_t)(STEPS - 1) * 128 + elem] = hrelu_prev;
}

// ---------------------------------------------------------------------------
// K2b: generic segment_min over edges: aggr[n] = min_{e: eidx[e]==n} msg[e]
// ---------------------------------------------------------------------------
__global__ __launch_bounds__(128) void k_aggmin(
    const float* __restrict__ msg, const int* __restrict__ eidx,
    float* __restrict__ aggr) {
  const int n = blockIdx.x, j = threadIdx.x;
  float m = __uint_as_float(0x7f800000u);  // +inf (segment_min identity)
  for (int e = 0; e < NEDGE; ++e) {
    if (eidx[e] == n) m = fminf(m, msg[(size_t)e * HM + j]);
  }
  aggr[(size_t)n * HM + j] = m;
}

// ---------------------------------------------------------------------------
// K3: XZu[n] += Wih_u[:,64:192] @ aggr[n]   (parallel, 320 blocks)
// ---------------------------------------------------------------------------
__global__ __launch_bounds__(256) void k_aggproj(
    const float* __restrict__ cva, const float* __restrict__ aggr,
    float* __restrict__ XZu) {
  const int n = blockIdx.x, tid = threadIdx.x;
  __shared__ float av[HM];
  if (tid < HM) av[tid] = aggr[(size_t)n * HM + tid];
  __syncthreads();
  for (int j = tid; j < ZU; j += 256) {
    const float* wr = cva + O_WU + j * DU + FN;
    float acc = 0.0f;
#pragma unroll
    for (int k = 0; k < HM; ++k) acc += wr[k] * av[k];
    XZu[(size_t)n * ZU + j] += acc;
  }
}

// ---------------------------------------------------------------------------
// K4b: generic segment_min over nodes: aggB[b] = min_{n: bidx[n]==b} upd[n]
// ---------------------------------------------------------------------------
__global__ __launch_bounds__(128) void k_aggbmin(
    const float* __restrict__ upd, const int* __restrict__ bidx,
    float* __restrict__ aggB) {
  const int b = blockIdx.x, j = threadIdx.x;
  float m = __uint_as_float(0x7f800000u);
  for (int n = 0; n < NNODE; ++n) {
    if (bidx[n] == b) m = fminf(m, upd[(size_t)n * HU + j]);
  }
  aggB[(size_t)b * HU + j] = m;
}

// ---------------------------------------------------------------------------
// K5: blocks [0,64): XZg[b] += Wih_g[:,0:128] @ aggB[b]
//     blocks [64,128): XZa[b] = Wih_a[:,0:128] @ chosen[b] + biases
// ---------------------------------------------------------------------------
__global__ __launch_bounds__(256) void k_gproj(
    const float* __restrict__ cva,
    const float* __restrict__ aggB, const float* __restrict__ upd,
    const int* __restrict__ bidx, const int* __restrict__ who,
    float* __restrict__ XZg, float* __restrict__ XZa) {
  const int blk = blockIdx.x, tid = threadIdx.x;
  __shared__ float buf[HU];
  __shared__ int satbw;
  if (blk < BG) {
    const int b = blk;
    if (tid < HU) buf[tid] = aggB[(size_t)b * HU + tid];
    __syncthreads();
    if (tid < ZG) {
      const float* wr = cva + O_WG + tid * DG;
      float acc = 0.0f;
#pragma unroll
      for (int k = 0; k < HU; ++k) acc += wr[k] * buf[k];
      XZg[(size_t)b * ZG + tid] += acc;
    }
  } else {
    const int b = blk - BG;
    const int whoB = who[b];
    if (tid == 0) {
      int off = 0;
      for (int i = 0; i < NNODE; ++i) off += (bidx[i] < b) ? 1 : 0;
      const int adj = (whoB == 3) ? 2 : whoB;
      satbw = (b == 0) ? who[0] : (adj + off);
    }
    __syncthreads();
    if (tid < HU) {
      float v;
      if (whoB == 3) v = aggB[(size_t)b * HU + tid];
      else v = upd[(size_t)satbw * HU + tid];
      buf[tid] = v;
    }
    __syncthreads();
    if (tid < ZA) {
      const float* wr = cva + O_WA + tid * DA;
      float acc = cva[O_BA + tid];
#pragma unroll
      for (int k = 0; k < HU; ++k) acc += wr[k] * buf[k];
      XZa[(size_t)b * ZA + tid] = acc;
    }
  }
}

// ---------------------------------------------------------------------------
// K6: group LSTM chain (64 steps, H=64) + action chain + softmax + fp32 out.
// ---------------------------------------------------------------------------
__global__ __launch_bounds__(256, 2) void k_final(
    const float* __restrict__ cva, const float* __restrict__ XZg,
    const float* __restrict__ XZa, float* __restrict__ out) {
  const int j = threadIdx.x;
  __shared__ __align__(16) float hg[HG];
  __shared__ float zsg[ZG];
  __shared__ float grp[BG * HG];
  __shared__ float za[ZA];
  __shared__ float haL[HA];
  __shared__ float res[BG * HA];

  float wg[HG];
  {
    const float* wr = cva + O_WHG + j * HG;
#pragma unroll
    for (int k = 0; k < HG; ++k) wg[k] = wr[k];
  }
  if (j < HG) hg[j] = 0.0f;
  float cg = 0.0f;
  __syncthreads();
  for (int b = 0; b < BG; ++b) {
    float acc = XZg[(size_t)b * ZG + j];
#pragma unroll
    for (int k = 0; k < HG; ++k) acc += wg[k] * hg[k];
    zsg[j] = acc;
    __syncthreads();
    if (j < HG) {
      float zi = zsg[j], zf = zsg[HG + j], zg = zsg[2 * HG + j], zo = zsg[3 * HG + j];
      cg = sigf(zf) * cg + sigf(zi) * tanh_(zg);
      float h = sigf(zo) * tanh_(cg);
      hg[j] = h;
      grp[b * HG + j] = fmaxf(h, 0.0f);
    }
    __syncthreads();
  }

  float wa2[HG];
  float wha[HA];
  if (j < ZA) {
    const float* wr2 = cva + O_WA + j * DA + HU;
#pragma unroll
    for (int k = 0; k < HG; ++k) wa2[k] = wr2[k];
#pragma unroll
    for (int k = 0; k < HA; ++k) wha[k] = cva[O_WHA + j * HA + k];
  }
  if (j < HA) haL[j] = 0.0f;
  float ca = 0.0f;
  __syncthreads();
  for (int b = 0; b < BG; ++b) {
    if (j < ZA) {
      float acc = XZa[(size_t)b * ZA + j];
#pragma unroll
      for (int k = 0; k < HG; ++k) acc += wa2[k] * grp[b * HG + k];
#pragma unroll
      for (int k = 0; k < HA; ++k) acc += wha[k] * haL[k];
      za[j] = acc;
    }
    __syncthreads();
    if (j < HA) {
      float zi = za[j], zf = za[HA + j], zg = za[2 * HA + j], zo = za[3 * HA + j];
      ca = sigf(zf) * ca + sigf(zi) * tanh_(zg);
      float h = sigf(zo) * tanh_(ca);
      haL[j] = h;
      res[b * HA + j] = h;
    }
    __syncthreads();
  }
  if (j < BG) {
    float x0 = res[j * 4 + 0], x1 = res[j * 4 + 1];
    float x2 = res[j * 4 + 2], x3 = res[j * 4 + 3];
    float m = fmaxf(fmaxf(x0, x1), fmaxf(x2, x3));
    float e0 = __expf(x0 - m), e1 = __expf(x1 - m);
    float e2 = __expf(x2 - m), e3 = __expf(x3 - m);
    float s = e0 + e1 + e2 + e3;
    out[j * 4 + 0] = e0 / s;
    out[j * 4 + 1] = e1 / s;
    out[j * 4 + 2] = e2 / s;
    out[j * 4 + 3] = e3 / s;
  }
}

__global__ void k_zero(float* out) { out[threadIdx.x] = 0.0f; }

extern "C" void kernel_launch(void* const* d_in, const int* in_sizes, int n_in,
                              void* d_out, int out_size, void* d_ws, size_t ws_size,
                              hipStream_t stream) {
  const void* nodes = d_in[0];
  const void* gattr = d_in[1];
  const int* eidx  = (const int*)d_in[2];
  const int* nn    = (const int*)d_in[3];
  const int* ne    = (const int*)d_in[4];
  const int* bidx  = (const int*)d_in[5];
  const int* who   = (const int*)d_in[6];

  if (ws_size < (size_t)WS_FLOATS * 4) {
    k_zero<<<1, 256, 0, stream>>>((float*)d_out);
    return;
  }

  float* ws = (float*)d_ws;
  int* flagp = (int*)d_ws;
  float* cva = ws + CV;
  float* XZm = cva + O_XZM;
  float* XZu = cva + O_XZU;
  float* XZg = cva + O_XZG;
  float* XZa = cva + O_XZA;
  float* aggr = cva + O_AGGR;
  float* aggB = cva + O_AGGB;
  float* upd = cva + O_UPD;
  float* msg = XZm;  // overlay (delayed-store ordering; see k_chain comment)

  k_detect<<<1, 64, 0, stream>>>((const u32*)nodes, flagp);
  k_convert<<<(CONV_TOTAL + 255) / 256, 256, 0, stream>>>(
      nodes, gattr,
      d_in[7], d_in[8], d_in[9], d_in[10],
      d_in[11], d_in[12], d_in[13], d_in[14],
      d_in[15], d_in[16], d_in[17], d_in[18],
      d_in[19], d_in[20], d_in[21], d_in[22],
      flagp, cva);
  k_pre<<<NEDGE + NNODE + BG, 256, 0, stream>>>(cva, eidx, nn, ne, XZm, XZu, XZg);
  k_chain<NEDGE><<<1, 1024, 0, stream>>>(cva + O_WHM, XZm, msg);
  k_aggmin<<<NNODE, 128, 0, stream>>>(msg, eidx, aggr);
  k_aggproj<<<NNODE, 256, 0, stream>>>(cva, aggr, XZu);
  k_chain<NNODE><<<1, 1024, 0, stream>>>(cva + O_WHU, XZu, upd);
  k_aggbmin<<<BG, 128, 0, stream>>>(upd, bidx, aggB);
  k_gproj<<<2 * BG, 256, 0, stream>>>(cva, aggB, upd, bidx, who, XZg, XZa);
  k_final<<<1, 256, 0, stream>>>(cva, XZg, XZa, (float*)d_out);
}